// Round 1
// baseline (87.792 us; speedup 1.0000x reference)
//
#include <hip/hip_runtime.h>

#define B 4
#define L 512
#define H 768
#define S 100
#define R 100
#define E 25
#define NE 10
#define NR 6
#define NEGF (-1e20f)
#define TPB 192            // 3 waves; each thread owns one float4 of the H=768 channels
#define NPROJ (NE + 2*NR)  // 22 fused per-entity outputs: [0,NE)=span logits,
                           // [NE,NE+NR)=head proj, [NE+NR,NPROJ)=tail proj

__device__ __forceinline__ float4 fmax4(float4 a, float4 b) {
    return make_float4(fmaxf(a.x, b.x), fmaxf(a.y, b.y),
                       fmaxf(a.z, b.z), fmaxf(a.w, b.w));
}

// Contiguous 0/1 span stats: n = popcount, start = first set index.
// Threads 0..127 read one int4 each (covers L=512). Per-wave ballots over the
// 4 components -> popcount/ctz in scalar regs; no shuffle chain.
// Wave w covers l in [256w, 256w+256): lane i <-> l = 4*(64w+i)+comp.
__device__ __forceinline__ void mask_stats(const int* __restrict__ mrow,
                                           int t, int wave, int lane,
                                           int* sc, int* sm, int& n, int& start)
{
    int4 m = make_int4(0, 0, 0, 0);
    if (t < L / 4) m = reinterpret_cast<const int4*>(mrow)[t];
    const unsigned long long b0 = __ballot(m.x != 0);
    const unsigned long long b1 = __ballot(m.y != 0);
    const unsigned long long b2 = __ballot(m.z != 0);
    const unsigned long long b3 = __ballot(m.w != 0);
    if (lane == 0 && wave < 2) {
        const int c = __popcll(b0) + __popcll(b1) + __popcll(b2) + __popcll(b3);
        int mn = L;
        if (b3) mn = min(mn, 4 * __builtin_ctzll(b3) + 3);
        if (b2) mn = min(mn, 4 * __builtin_ctzll(b2) + 2);
        if (b1) mn = min(mn, 4 * __builtin_ctzll(b1) + 1);
        if (b0) mn = min(mn, 4 * __builtin_ctzll(b0));
        sc[wave] = c;
        sm[wave] = (mn < L) ? (256 * wave + mn) : L;
    }
    __syncthreads();
    n = sc[0] + sc[1];
    start = min(sm[0], sm[1]);
}

// Max-pool rows [start, start+n): 8-way row unroll, row index clamped to
// n-1 (idempotent for max; start+n-1 <= 459 < L so reads stay in-bounds).
__device__ __forceinline__ float4 span_pool4(const float* __restrict__ hb,
                                             int start, int n, int t)
{
    const int st = H / 4;  // row stride in float4
    const float4* base = reinterpret_cast<const float4*>(hb) + (size_t)start * st + t;
    float4 a0 = make_float4(NEGF, NEGF, NEGF, NEGF);
    float4 a1 = a0, a2 = a0, a3 = a0, a4 = a0, a5 = a0, a6 = a0, a7 = a0;
    const int last = n - 1;
    for (int i = 0; i < n; i += 8) {
        const float4 v0 = base[(size_t)min(i + 0, last) * st];
        const float4 v1 = base[(size_t)min(i + 1, last) * st];
        const float4 v2 = base[(size_t)min(i + 2, last) * st];
        const float4 v3 = base[(size_t)min(i + 3, last) * st];
        const float4 v4 = base[(size_t)min(i + 4, last) * st];
        const float4 v5 = base[(size_t)min(i + 5, last) * st];
        const float4 v6 = base[(size_t)min(i + 6, last) * st];
        const float4 v7 = base[(size_t)min(i + 7, last) * st];
        a0 = fmax4(a0, v0); a1 = fmax4(a1, v1);
        a2 = fmax4(a2, v2); a3 = fmax4(a3, v3);
        a4 = fmax4(a4, v4); a5 = fmax4(a5, v5);
        a6 = fmax4(a6, v6); a7 = fmax4(a7, v7);
    }
    return fmax4(fmax4(fmax4(a0, a1), fmax4(a2, a3)),
                 fmax4(fmax4(a4, a5), fmax4(a6, a7)));
}

// Reduce p[NO] across the 192-thread block; thread t<NO gets the total.
template <int NO>
__device__ __forceinline__ float block_reduce(const float* p, int t, int wave, int lane,
                                              float sred[3][NPROJ])
{
    #pragma unroll
    for (int o = 0; o < NO; ++o) {
        float v = p[o];
        #pragma unroll
        for (int off = 32; off > 0; off >>= 1) v += __shfl_down(v, off, 64);
        if (lane == 0) sred[wave][o] = v;
    }
    __syncthreads();
    return (t < NO) ? (sred[0][t] + sred[1][t] + sred[2][t]) : 0.0f;
}

// ---------------------------------------------------------------------------
// K1: one block per span. Pools in registers, then projects the pooled vector
// straight to the logit space (everything downstream is linear):
//   entity block (j<S):  22 outputs = NE span logits (written final, +b_span)
//                        + NR head-proj + NR tail-proj (ws, size terms folded in)
//   context block (j>=S): NR ctx-proj outputs (ws, b_rel folded in)
// The (B,S,H)/(B,R,H) intermediates are never materialized.
// grid = B*(S+R), block = 192
// ---------------------------------------------------------------------------
__global__ __launch_bounds__(TPB) void pool_kernel(
    const float* __restrict__ hidden,     // (B, L, H)
    const int*   __restrict__ emask,      // (B, S, L)
    const int*   __restrict__ cmask,      // (B, R, L)
    const float* __restrict__ size_emb,   // (MAXLEN, E)
    const float* __restrict__ w_span,     // (H+E, NE)
    const float* __restrict__ b_span,     // (NE,)
    const float* __restrict__ w_rel,      // (3H+2E, NR)
    const float* __restrict__ b_rel,      // (NR,)
    float* __restrict__ ent_proj,         // ws: (B, S, 2*NR)  [head NR | tail NR]
    float* __restrict__ ctx_proj,         // ws: (B, R, NR)    bias included
    float* __restrict__ ent_logits)       // out: (B, S, NE)
{
    const int idx  = blockIdx.x;
    const int b    = idx / (S + R);
    const int j    = idx % (S + R);
    const int t    = threadIdx.x;
    const int wave = t >> 6;
    const int lane = t & 63;

    __shared__ int   sc[2], sm[2];
    __shared__ float sred[3][NPROJ];

    const float* hb = hidden + (size_t)b * L * H;
    const int* mrow = (j < S) ? (emask + (size_t)(b * S + j) * L)
                              : (cmask + (size_t)(b * R + (j - S)) * L);
    int n, start;
    mask_stats(mrow, t, wave, lane, sc, sm, n, start);

    const float4 mv = span_pool4(hb, start, n, t);

    if (j >= S) {
        // context span: only its NR-dim projection is ever needed
        float p[NR];
        const float* wc = w_rel + (size_t)(4 * t) * NR;
        #pragma unroll
        for (int o = 0; o < NR; ++o)
            p[o] = mv.x * wc[o] + mv.y * wc[NR + o]
                 + mv.z * wc[2 * NR + o] + mv.w * wc[3 * NR + o];
        const float r = block_reduce<NR>(p, t, wave, lane, sred);
        if (t < NR)
            ctx_proj[(size_t)(b * R + (j - S)) * NR + t] = r + b_rel[t];
        return;
    }

    // entity span: span logits + head/tail relation projections, fused
    float p[NPROJ];
    const float* w0 = w_span + (size_t)(4 * t) * NE;           // rows 4t..4t+3
    const float* wh = w_rel  + (size_t)(H + 4 * t) * NR;       // head block
    const float* wt = w_rel  + (size_t)(2 * H + 4 * t) * NR;   // tail block
    #pragma unroll
    for (int o = 0; o < NE; ++o)
        p[o] = mv.x * w0[o] + mv.y * w0[NE + o]
             + mv.z * w0[2 * NE + o] + mv.w * w0[3 * NE + o];
    #pragma unroll
    for (int o = 0; o < NR; ++o) {
        p[NE + o]      = mv.x * wh[o] + mv.y * wh[NR + o]
                       + mv.z * wh[2 * NR + o] + mv.w * wh[3 * NR + o];
        p[NE + NR + o] = mv.x * wt[o] + mv.y * wt[NR + o]
                       + mv.z * wt[2 * NR + o] + mv.w * wt[3 * NR + o];
    }
    if (t < E) {  // size-embedding terms (span + head-size + tail-size rows)
        const float sz = size_emb[(size_t)n * E + t];
        #pragma unroll
        for (int o = 0; o < NE; ++o)
            p[o] += sz * w_span[(size_t)(H + t) * NE + o];
        #pragma unroll
        for (int o = 0; o < NR; ++o) {
            p[NE + o]      += sz * w_rel[(size_t)(3 * H + t) * NR + o];
            p[NE + NR + o] += sz * w_rel[(size_t)(3 * H + E + t) * NR + o];
        }
    }
    const float r = block_reduce<NPROJ>(p, t, wave, lane, sred);
    if (t < NE)
        ent_logits[(size_t)(b * S + j) * NE + t] = r + b_span[t];
    else if (t < NPROJ)
        ent_proj[(size_t)(b * S + j) * (2 * NR) + (t - NE)] = r;
}

// ---------------------------------------------------------------------------
// K2: relation logits are now just 2400 scalar gathers+adds.
// out[b,r,o] = ctx_proj[b,r,o] (has b_rel) + head_proj[o] + tail_proj[o]
// grid = ceil(B*R*NR/256) = 10 blocks
// ---------------------------------------------------------------------------
__global__ __launch_bounds__(256) void combine_kernel(
    const float* __restrict__ ent_proj,   // (B, S, 2*NR)
    const float* __restrict__ ctx_proj,   // (B, R, NR)
    const int*   __restrict__ relations,  // (B, R, 2)
    float* __restrict__ rel_logits)       // out: (B, R, NR)
{
    const int g = blockIdx.x * 256 + threadIdx.x;
    if (g >= B * R * NR) return;
    const int o  = g % NR;
    const int br = g / NR;        // b*R + r
    const int b  = br / R;
    const int head = relations[(size_t)br * 2 + 0];
    const int tail = relations[(size_t)br * 2 + 1];
    rel_logits[g] = ctx_proj[g]
                  + ent_proj[(size_t)(b * S + head) * (2 * NR) + o]
                  + ent_proj[(size_t)(b * S + tail) * (2 * NR) + NR + o];
}

extern "C" void kernel_launch(void* const* d_in, const int* in_sizes, int n_in,
                              void* d_out, int out_size, void* d_ws, size_t ws_size,
                              hipStream_t stream) {
    const float* hidden    = (const float*)d_in[0];
    const int*   emask     = (const int*)  d_in[1];
    const int*   relations = (const int*)  d_in[2];
    const int*   cmask     = (const int*)  d_in[3];
    const float* size_emb  = (const float*)d_in[4];
    const float* w_span    = (const float*)d_in[5];
    const float* b_span    = (const float*)d_in[6];
    const float* w_rel     = (const float*)d_in[7];
    const float* b_rel     = (const float*)d_in[8];

    float* out        = (float*)d_out;
    float* ent_logits = out;                 // (B, S, NE) = 4000 floats
    float* rel_logits = out + B * S * NE;    // (B, R, NR) = 2400 floats

    float* ws       = (float*)d_ws;
    float* ent_proj = ws;                              // B*S*2*NR = 4800 floats
    float* ctx_proj = ent_proj + (size_t)B * S * 2 * NR; // B*R*NR = 2400 floats

    pool_kernel<<<B * (S + R), TPB, 0, stream>>>(
        hidden, emask, cmask, size_emb, w_span, b_span, w_rel, b_rel,
        ent_proj, ctx_proj, ent_logits);

    combine_kernel<<<(B * R * NR + 255) / 256, 256, 0, stream>>>(
        ent_proj, ctx_proj, relations, rel_logits);
}